// Round 12
// baseline (132.537 us; speedup 1.0000x reference)
//
#include <hip/hip_runtime.h>
#include <hip/hip_fp16.h>
#include <math.h>

#define NEG_SLOPE 0.2f

typedef _Float16 f16x2 __attribute__((ext_vector_type(2)));
typedef _Float16 f16x8 __attribute__((ext_vector_type(8)));
typedef float f32x4 __attribute__((ext_vector_type(4)));

__device__ __forceinline__ float fdot2f(unsigned int a, unsigned int b, float c) {
#if __has_builtin(__builtin_amdgcn_fdot2)
    return __builtin_amdgcn_fdot2(__builtin_bit_cast(f16x2, a),
                                  __builtin_bit_cast(f16x2, b), c, false);
#else
    __half2 ah = __builtin_bit_cast(__half2, a), bh = __builtin_bit_cast(__half2, b);
    float2 af = __half22float2(ah), bf = __half22float2(bh);
    return c + af.x * bf.x + af.y * bf.y;
#endif
}

// ---------------------------------------------------------------------------
// Kernel 0: fused prep (blocks 0..63) + segment offsets (blocks 64..).
// ---------------------------------------------------------------------------
__global__ __launch_bounds__(256) void prep_seg_kernel(
    const float* __restrict__ W, __half* __restrict__ w16t,
    const int* __restrict__ dst, int* __restrict__ off, int E, int N)
{
    const int b = blockIdx.x;
    if (b < 64) {                                  // W fp32 [k][c] -> fp16 [c][k]
        int tid = b * 256 + threadIdx.x;
        int c = tid >> 7, k = tid & 127;
        w16t[c * 128 + k] = __float2half(W[k * 128 + c]);
        return;
    }
    int i = (b - 64) * 256 + threadIdx.x;
    if (i >= E) return;
    int d = dst[i];
    int prev = (i == 0) ? -1 : dst[i - 1];
    for (int n = prev + 1; n <= d; ++n) off[n] = i;
    if (i == E - 1) {
        for (int n = d + 1; n <= N; ++n) off[n] = E;
    }
}

// ---------------------------------------------------------------------------
// Kernel 1: proj — feat16 = fp16(h) @ fp16(W) via MFMA 16x16x32_f16,
// fused el/er epilogue + LDS-transpose repack for coalesced feat stores.
// ---------------------------------------------------------------------------
__global__ __launch_bounds__(256) void proj_kernel(
    const float* __restrict__ h, const __half* __restrict__ w16t,
    const float* __restrict__ attn_l, const float* __restrict__ attn_r,
    __half* __restrict__ feat, float* __restrict__ el, float* __restrict__ er,
    int N)
{
    __shared__ __half hl[64 * 128];               // h tile, later reused as out tile
    __shared__ __half wl[128 * 128];
    const int t = threadIdx.x;
    const int nodeBase = blockIdx.x * 64;

#pragma unroll
    for (int i = 0; i < 8; ++i) {
        int ch = t + i * 256;                     // 2048 16B chunks
        int col = ch >> 4, k8 = ch & 15;
        uint4 v = *(const uint4*)(w16t + col * 128 + k8 * 8);
        int byte = col * 256 + k8 * 16;
        *(uint4*)((char*)wl + (byte ^ ((col & 7) << 4))) = v;
    }
#pragma unroll
    for (int i = 0; i < 8; ++i) {
        int slot = t + i * 256;                   // 2048 float4 slots
        int row = slot >> 5, c4 = slot & 31;
        int gn = nodeBase + row;
        float4 v = make_float4(0.f, 0.f, 0.f, 0.f);
        if (gn < N) v = *(const float4*)(h + (size_t)gn * 128 + c4 * 4);
        __half2 p0 = __floats2half2_rn(v.x, v.y);
        __half2 p1 = __floats2half2_rn(v.z, v.w);
        uint2 u = make_uint2(__builtin_bit_cast(unsigned int, p0),
                             __builtin_bit_cast(unsigned int, p1));
        int byte = row * 256 + c4 * 8;
        *(uint2*)((char*)hl + (byte ^ ((row & 7) << 4))) = u;
    }
    __syncthreads();

    const int l = t & 63, wave = t >> 6;
    const int arow = wave * 16 + (l & 15);
    const int kg = l >> 4;
    f32x4 acc[8];
#pragma unroll
    for (int i = 0; i < 8; ++i) acc[i] = (f32x4){0.f, 0.f, 0.f, 0.f};

#pragma unroll
    for (int kt = 0; kt < 4; ++kt) {
        const int kb = (kt * 32 + kg * 8) * 2;
        f16x8 a = *(const f16x8*)((const char*)hl +
                    ((arow * 256 + kb) ^ ((arow & 7) << 4)));
#pragma unroll
        for (int ct = 0; ct < 8; ++ct) {
            int bcol = ct * 16 + (l & 15);
            f16x8 b = *(const f16x8*)((const char*)wl +
                        ((bcol * 256 + kb) ^ ((bcol & 7) << 4)));
            acc[ct] = __builtin_amdgcn_mfma_f32_16x16x32_f16(a, b, acc[ct], 0, 0, 0);
        }
    }

    __syncthreads();                              // all waves done reading hl
    const int colLo = l & 15;
    const int rowHi = wave * 16 + (l >> 4) * 4;
#pragma unroll
    for (int ct = 0; ct < 8; ++ct) {
#pragma unroll
        for (int r = 0; r < 4; ++r) {
            int row = rowHi + r;
            int byte = row * 256 + (ct * 16 + colLo) * 2;
            *(__half*)((char*)hl + (byte ^ ((row & 7) << 4))) = __float2half(acc[ct][r]);
        }
    }

    float pl[4][4], pr[4][4];                     // [head][row]
#pragma unroll
    for (int hh = 0; hh < 4; ++hh) {
        float al0 = attn_l[hh * 32 + colLo];
        float al1 = attn_l[hh * 32 + 16 + colLo];
        float ar0 = attn_r[hh * 32 + colLo];
        float ar1 = attn_r[hh * 32 + 16 + colLo];
#pragma unroll
        for (int r = 0; r < 4; ++r) {
            pl[hh][r] = acc[2 * hh][r] * al0 + acc[2 * hh + 1][r] * al1;
            pr[hh][r] = acc[2 * hh][r] * ar0 + acc[2 * hh + 1][r] * ar1;
        }
    }
#pragma unroll
    for (int msk = 1; msk <= 8; msk <<= 1) {
#pragma unroll
        for (int hh = 0; hh < 4; ++hh)
#pragma unroll
            for (int r = 0; r < 4; ++r) {
                pl[hh][r] += __shfl_xor(pl[hh][r], msk);
                pr[hh][r] += __shfl_xor(pr[hh][r], msk);
            }
    }
    if (colLo == 0) {
#pragma unroll
        for (int r = 0; r < 4; ++r) {
            int node = nodeBase + rowHi + r;
            if (node < N) {
                *(float4*)(el + (size_t)node * 4) =
                    make_float4(pl[0][r], pl[1][r], pl[2][r], pl[3][r]);
                *(float4*)(er + (size_t)node * 4) =
                    make_float4(pr[0][r], pr[1][r], pr[2][r], pr[3][r]);
            }
        }
    }
    __syncthreads();

    char* featB = (char*)feat + (size_t)nodeBase * 256;
#pragma unroll
    for (int i = 0; i < 4; ++i) {
        int c = t + i * 256;
        int row = c >> 4;
        uint4 v = *(const uint4*)((const char*)hl + ((c * 16) ^ ((row & 7) << 4)));
        if (nodeBase + row < N) *(uint4*)(featB + c * 16) = v;
    }
}

// ---------------------------------------------------------------------------
// Kernel 2: edge weights, all 4 heads per thread (head-major streams).
// ---------------------------------------------------------------------------
__global__ __launch_bounds__(256) void edgew_kernel(
    const float* __restrict__ el, const float* __restrict__ er,
    const int* __restrict__ src, const int* __restrict__ dst,
    __half* __restrict__ w_t, int E)
{
    int e = blockIdx.x * 256 + threadIdx.x;
    if (e >= E) return;
    int sv = src[e], dv = dst[e];
    float4 a = *(const float4*)(el + (size_t)sv * 4);
    float4 b = *(const float4*)(er + (size_t)dv * 4);
    float s0 = a.x + b.x, s1 = a.y + b.y, s2 = a.z + b.z, s3 = a.w + b.w;
    s0 = s0 > 0.f ? s0 : NEG_SLOPE * s0;
    s1 = s1 > 0.f ? s1 : NEG_SLOPE * s1;
    s2 = s2 > 0.f ? s2 : NEG_SLOPE * s2;
    s3 = s3 > 0.f ? s3 : NEG_SLOPE * s3;
    w_t[e]                 = __float2half(__expf(s0));
    w_t[(size_t)E + e]     = __float2half(__expf(s1));
    w_t[(size_t)2 * E + e] = __float2half(__expf(s2));
    w_t[(size_t)3 * E + e] = __float2half(__expf(s3));
}

// ---------------------------------------------------------------------------
// Kernel 3: split-wave aggregate. Block = 256 thr = 4 waves = 2 nodes x
// 2 waves. Each wave processes half of its node's edge-pairs (even-aligned
// split keeps w2 dword loads aligned); partials combined through LDS.
// Doubles segment-level memory parallelism vs 1 wave/node.
// ---------------------------------------------------------------------------
__global__ __launch_bounds__(256) void aggregate_kernel(
    const __half* __restrict__ feat, const __half* __restrict__ w_t,
    const int* __restrict__ off, const int* __restrict__ src,
    const float* __restrict__ bias, float* __restrict__ out, int N, int E)
{
    __shared__ float part_ax[2][64];
    __shared__ float part_ay[2][64];
    __shared__ float part_dn[2][64];

    const int wave = threadIdx.x >> 6, l = threadIdx.x & 63;
    const int p = wave >> 1, sub = wave & 1;
    const int n0 = blockIdx.x * 2 + p;
    const bool active = (n0 < N);
    const int n = __builtin_amdgcn_readfirstlane(active ? n0 : 0);
    int s = off[n];                                      // s_load
    const int e = off[n + 1];                            // s_load
    const int f0 = 2 * l;
    const int hm = l >> 4;
    const __half* wp = w_t + (size_t)hm * E;
    float ax = 0.f, ay = 0.f, dn = 0.f;
    const unsigned int one2 = 0x3C003C00u;

    if (active && s < e) {
        int a0 = s;
        if (s & 1) {                                     // odd start: sub0 scalar
            if (sub == 0) {
                int sv = src[s];
                float w = __half2float(wp[s]);
                __half2 gh = *(const __half2*)(feat + (size_t)sv * 128 + f0);
                float2 fv = __half22float2(gh);
                ax += w * fv.x; ay += w * fv.y; dn += w;
            }
            a0 = s + 1;
        }
        const int cnt = e - a0;
        const int pairs = cnt >> 1;
        const int ph0 = pairs >> 1;
        int lo, hi;
        if (sub == 0) { lo = a0;           hi = a0 + 2 * ph0;   }
        else          { lo = a0 + 2 * ph0; hi = a0 + 2 * pairs; }

        int ei = lo;
        for (; ei + 16 <= hi; ei += 16) {
            int sv[16];
#pragma unroll
            for (int k = 0; k < 16; ++k) sv[k] = src[ei + k];    // s_loads
            const __half* wpb = wp + ei;
            unsigned int w2[8];
#pragma unroll
            for (int k = 0; k < 8; ++k) w2[k] = *(const unsigned int*)(wpb + 2 * k);
            unsigned int g[16];
#pragma unroll
            for (int k = 0; k < 16; ++k)
                g[k] = *(const unsigned int*)(feat + (size_t)sv[k] * 128 + f0);
#pragma unroll
            for (int k = 0; k < 8; ++k) {
                unsigned int lo_ = __builtin_amdgcn_perm(g[2 * k + 1], g[2 * k], 0x05040100u);
                unsigned int hi_ = __builtin_amdgcn_perm(g[2 * k + 1], g[2 * k], 0x07060302u);
                ax = fdot2f(w2[k], lo_, ax);
                ay = fdot2f(w2[k], hi_, ay);
                dn = fdot2f(w2[k], one2, dn);
            }
        }
        if (ei + 8 <= hi) {
            int sv[8];
#pragma unroll
            for (int k = 0; k < 8; ++k) sv[k] = src[ei + k];
            const __half* wpb = wp + ei;
            unsigned int w2[4];
#pragma unroll
            for (int k = 0; k < 4; ++k) w2[k] = *(const unsigned int*)(wpb + 2 * k);
            unsigned int g[8];
#pragma unroll
            for (int k = 0; k < 8; ++k)
                g[k] = *(const unsigned int*)(feat + (size_t)sv[k] * 128 + f0);
#pragma unroll
            for (int k = 0; k < 4; ++k) {
                unsigned int lo_ = __builtin_amdgcn_perm(g[2 * k + 1], g[2 * k], 0x05040100u);
                unsigned int hi_ = __builtin_amdgcn_perm(g[2 * k + 1], g[2 * k], 0x07060302u);
                ax = fdot2f(w2[k], lo_, ax);
                ay = fdot2f(w2[k], hi_, ay);
                dn = fdot2f(w2[k], one2, dn);
            }
            ei += 8;
        }
        if (ei + 4 <= hi) {
            int sv0 = src[ei], sv1 = src[ei + 1], sv2 = src[ei + 2], sv3 = src[ei + 3];
            unsigned int w2a = *(const unsigned int*)(wp + ei);
            unsigned int w2b = *(const unsigned int*)(wp + ei + 2);
            unsigned int g0 = *(const unsigned int*)(feat + (size_t)sv0 * 128 + f0);
            unsigned int g1 = *(const unsigned int*)(feat + (size_t)sv1 * 128 + f0);
            unsigned int g2 = *(const unsigned int*)(feat + (size_t)sv2 * 128 + f0);
            unsigned int g3 = *(const unsigned int*)(feat + (size_t)sv3 * 128 + f0);
            unsigned int lo_ = __builtin_amdgcn_perm(g1, g0, 0x05040100u);
            unsigned int hi_ = __builtin_amdgcn_perm(g1, g0, 0x07060302u);
            ax = fdot2f(w2a, lo_, ax); ay = fdot2f(w2a, hi_, ay); dn = fdot2f(w2a, one2, dn);
            lo_ = __builtin_amdgcn_perm(g3, g2, 0x05040100u);
            hi_ = __builtin_amdgcn_perm(g3, g2, 0x07060302u);
            ax = fdot2f(w2b, lo_, ax); ay = fdot2f(w2b, hi_, ay); dn = fdot2f(w2b, one2, dn);
            ei += 4;
        }
        if (ei + 2 <= hi) {
            int sv0 = src[ei], sv1 = src[ei + 1];
            unsigned int w2 = *(const unsigned int*)(wp + ei);
            unsigned int g0 = *(const unsigned int*)(feat + (size_t)sv0 * 128 + f0);
            unsigned int g1 = *(const unsigned int*)(feat + (size_t)sv1 * 128 + f0);
            unsigned int lo_ = __builtin_amdgcn_perm(g1, g0, 0x05040100u);
            unsigned int hi_ = __builtin_amdgcn_perm(g1, g0, 0x07060302u);
            ax = fdot2f(w2, lo_, ax); ay = fdot2f(w2, hi_, ay); dn = fdot2f(w2, one2, dn);
            ei += 2;
        }
        if (sub == 1 && (cnt & 1)) {                     // odd tail: last edge
            int idx = e - 1;
            int sv = src[idx];
            float w = __half2float(wp[idx]);
            __half2 gh = *(const __half2*)(feat + (size_t)sv * 128 + f0);
            float2 fv = __half22float2(gh);
            ax += w * fv.x; ay += w * fv.y; dn += w;
        }
    }

    if (sub == 1) {
        part_ax[p][l] = ax;
        part_ay[p][l] = ay;
        part_dn[p][l] = dn;
    }
    __syncthreads();
    if (active && sub == 0) {
        const float b0 = bias[f0], b1 = bias[f0 + 1];
        float* outp = out + (size_t)n * 128;
        if (s >= e) {
            outp[f0]     = fmaxf(b0, 0.f);
            outp[f0 + 1] = fmaxf(b1, 0.f);
        } else {
            ax += part_ax[p][l];
            ay += part_ay[p][l];
            dn += part_dn[p][l];
            const float inv = 1.f / dn;
            *(float2*)(outp + f0) = make_float2(fmaxf(ax * inv + b0, 0.f),
                                                fmaxf(ay * inv + b1, 0.f));
        }
    }
}

// ---------------------------------------------------------------------------
extern "C" void kernel_launch(void* const* d_in, const int* in_sizes, int n_in,
                              void* d_out, int out_size, void* d_ws, size_t ws_size,
                              hipStream_t stream)
{
    const float* h      = (const float*)d_in[0];
    const int*   src    = (const int*)d_in[1];
    const int*   dst    = (const int*)d_in[2];
    const float* W      = (const float*)d_in[3];
    const float* attn_l = (const float*)d_in[4];
    const float* attn_r = (const float*)d_in[5];
    const float* bias   = (const float*)d_in[6];
    const int N = in_sizes[0] / 128;
    const int E = in_sizes[1];
    float* out = (float*)d_out;

    // workspace (all offsets multiples of 16B)
    char* ws = (char*)d_ws;
    __half* feat = (__half*)ws;            ws += (size_t)N * 128 * sizeof(__half); // 25.6MB
    float*  el   = (float*)ws;             ws += (size_t)N * 4 * sizeof(float);    // 1.6MB
    float*  er   = (float*)ws;             ws += (size_t)N * 4 * sizeof(float);    // 1.6MB
    __half* w_t  = (__half*)ws;            ws += (size_t)E * 4 * sizeof(__half);   // 12.8MB
    __half* w16t = (__half*)ws;            ws += 128 * 128 * sizeof(__half);       // 32KB
    int*    off  = (int*)ws;

    hipLaunchKernelGGL(prep_seg_kernel, dim3(64 + (E + 255) / 256), dim3(256), 0, stream,
                       W, w16t, dst, off, E, N);
    hipLaunchKernelGGL(proj_kernel, dim3((N + 63) / 64), dim3(256), 0, stream,
                       h, w16t, attn_l, attn_r, feat, el, er, N);
    hipLaunchKernelGGL(edgew_kernel, dim3((E + 255) / 256), dim3(256), 0, stream,
                       el, er, src, dst, w_t, E);
    hipLaunchKernelGGL(aggregate_kernel, dim3((N + 1) / 2), dim3(256), 0, stream,
                       feat, w_t, off, src, bias, out, N, E);
}

// Round 13
// 103.320 us; speedup vs baseline: 1.2828x; 1.2828x over previous
//
#include <hip/hip_runtime.h>
#include <hip/hip_fp16.h>
#include <math.h>

#define NEG_SLOPE 0.2f

typedef _Float16 f16x2 __attribute__((ext_vector_type(2)));
typedef _Float16 f16x8 __attribute__((ext_vector_type(8)));
typedef float f32x4 __attribute__((ext_vector_type(4)));

__device__ __forceinline__ float fdot2f(unsigned int a, unsigned int b, float c) {
#if __has_builtin(__builtin_amdgcn_fdot2)
    return __builtin_amdgcn_fdot2(__builtin_bit_cast(f16x2, a),
                                  __builtin_bit_cast(f16x2, b), c, false);
#else
    __half2 ah = __builtin_bit_cast(__half2, a), bh = __builtin_bit_cast(__half2, b);
    float2 af = __half22float2(ah), bf = __half22float2(bh);
    return c + af.x * bf.x + af.y * bf.y;
#endif
}

__device__ __forceinline__ unsigned int packw(float a, float b) {
#if __has_builtin(__builtin_amdgcn_cvt_pkrtz)
    return __builtin_bit_cast(unsigned int, __builtin_amdgcn_cvt_pkrtz(a, b));
#else
    return __builtin_bit_cast(unsigned int, __floats2half2_rn(a, b));
#endif
}

// ---------------------------------------------------------------------------
// Kernel 0: fused prep (blocks 0..63: W->fp16 transpose, + attn vecs) +
// segment offsets (blocks 64..).
// ---------------------------------------------------------------------------
__global__ __launch_bounds__(256) void prep_seg_kernel(
    const float* __restrict__ W, __half* __restrict__ w16t,
    const float* __restrict__ attn_l, const float* __restrict__ attn_r,
    __half* __restrict__ al16, __half* __restrict__ ar16,
    const int* __restrict__ dst, int* __restrict__ off, int E, int N)
{
    const int b = blockIdx.x;
    if (b < 64) {                                  // W fp32 [k][c] -> fp16 [c][k]
        int tid = b * 256 + threadIdx.x;
        int c = tid >> 7, k = tid & 127;
        w16t[c * 128 + k] = __float2half(W[k * 128 + c]);
        if (tid < 128) {
            al16[tid] = __float2half(attn_l[tid]);
            ar16[tid] = __float2half(attn_r[tid]);
        }
        return;
    }
    int i = (b - 64) * 256 + threadIdx.x;
    if (i >= E) return;
    int d = dst[i];
    int prev = (i == 0) ? -1 : dst[i - 1];
    for (int n = prev + 1; n <= d; ++n) off[n] = i;
    if (i == E - 1) {
        for (int n = d + 1; n <= N; ++n) off[n] = E;
    }
}

// ---------------------------------------------------------------------------
// Kernel 1: proj — 128-node x 128-col tile, 512 threads (8 waves), MFMA
// 16x16x32_f16. Epilogue: repack acc -> LDS row-major (swizzled), then
// el/er via LDS reads (thread=(row,head), no cross-lane reduce, coalesced
// stores) + coalesced feat stores.
// ---------------------------------------------------------------------------
__global__ __launch_bounds__(512) void proj_kernel(
    const float* __restrict__ h, const __half* __restrict__ w16t,
    const __half* __restrict__ al16, const __half* __restrict__ ar16,
    __half* __restrict__ feat, float* __restrict__ el, float* __restrict__ er,
    int N)
{
    __shared__ __half hl[128 * 128];              // h tile, later out tile (32KB)
    __shared__ __half wl[128 * 128];              // W tile (32KB)
    const int t = threadIdx.x;
    const int nodeBase = blockIdx.x * 128;

    // stage W16t -> wl (swizzled): 2048 16B chunks, 4/thread
#pragma unroll
    for (int i = 0; i < 4; ++i) {
        int ch = t + i * 512;
        int col = ch >> 4, k8 = ch & 15;
        uint4 v = *(const uint4*)(w16t + col * 128 + k8 * 8);
        int byte = col * 256 + k8 * 16;
        *(uint4*)((char*)wl + (byte ^ ((col & 7) << 4))) = v;
    }
    // stage h (fp32 -> fp16) -> hl swizzled: 4096 float4 slots, 8/thread
#pragma unroll
    for (int i = 0; i < 8; ++i) {
        int slot = t + i * 512;
        int row = slot >> 5, c4 = slot & 31;
        int gn = nodeBase + row;
        float4 v = make_float4(0.f, 0.f, 0.f, 0.f);
        if (gn < N) v = *(const float4*)(h + (size_t)gn * 128 + c4 * 4);
        __half2 p0 = __floats2half2_rn(v.x, v.y);
        __half2 p1 = __floats2half2_rn(v.z, v.w);
        uint2 u = make_uint2(__builtin_bit_cast(unsigned int, p0),
                             __builtin_bit_cast(unsigned int, p1));
        int byte = row * 256 + c4 * 8;
        *(uint2*)((char*)hl + (byte ^ ((row & 7) << 4))) = u;
    }
    __syncthreads();

    const int l = t & 63, wave = t >> 6;          // 8 waves
    const int arow = wave * 16 + (l & 15);        // rows 0..127
    const int kg = l >> 4;
    f32x4 acc[8];
#pragma unroll
    for (int i = 0; i < 8; ++i) acc[i] = (f32x4){0.f, 0.f, 0.f, 0.f};

#pragma unroll
    for (int kt = 0; kt < 4; ++kt) {
        const int kb = (kt * 32 + kg * 8) * 2;
        f16x8 a = *(const f16x8*)((const char*)hl +
                    ((arow * 256 + kb) ^ ((arow & 7) << 4)));
#pragma unroll
        for (int ct = 0; ct < 8; ++ct) {
            int bcol = ct * 16 + (l & 15);
            f16x8 b = *(const f16x8*)((const char*)wl +
                        ((bcol * 256 + kb) ^ ((bcol & 7) << 4)));
            acc[ct] = __builtin_amdgcn_mfma_f32_16x16x32_f16(a, b, acc[ct], 0, 0, 0);
        }
    }

    __syncthreads();                              // all waves done reading hl
    // repack D-layout -> row-major fp16 tile in hl (swizzled)
    const int colLo = l & 15;
    const int rowHi = wave * 16 + (l >> 4) * 4;
#pragma unroll
    for (int ct = 0; ct < 8; ++ct) {
#pragma unroll
        for (int r = 0; r < 4; ++r) {
            int row = rowHi + r;
            int byte = row * 256 + (ct * 16 + colLo) * 2;
            *(__half*)((char*)hl + (byte ^ ((row & 7) << 4))) = __float2half(acc[ct][r]);
        }
    }
    __syncthreads();                              // tile complete

    // ---- el/er from LDS: thread = (row = t>>2, head = t&3); stores coalesced
    {
        const int row = t >> 2, head = t & 3;
        const int node = nodeBase + row;
        float lv = 0.f, rv = 0.f;
#pragma unroll
        for (int j = 0; j < 4; ++j) {
            int byte = row * 256 + head * 64 + j * 16;
            uint4 f = *(const uint4*)((const char*)hl + (byte ^ ((row & 7) << 4)));
            uint4 a = *(const uint4*)(al16 + head * 32 + j * 8);
            uint4 bb = *(const uint4*)(ar16 + head * 32 + j * 8);
            lv = fdot2f(f.x, a.x, lv); rv = fdot2f(f.x, bb.x, rv);
            lv = fdot2f(f.y, a.y, lv); rv = fdot2f(f.y, bb.y, rv);
            lv = fdot2f(f.z, a.z, lv); rv = fdot2f(f.z, bb.z, rv);
            lv = fdot2f(f.w, a.w, lv); rv = fdot2f(f.w, bb.w, rv);
        }
        if (node < N) {
            el[(size_t)node * 4 + head] = lv;     // addr = nodeBase*4 + t: coalesced
            er[(size_t)node * 4 + head] = rv;
        }
    }

    // ---- coalesced feat stores: 2048 16B chunks, 4/thread
    char* featB = (char*)feat + (size_t)nodeBase * 256;
#pragma unroll
    for (int i = 0; i < 4; ++i) {
        int c = t + i * 512;
        int row = c >> 4;
        uint4 v = *(const uint4*)((const char*)hl + ((c * 16) ^ ((row & 7) << 4)));
        if (nodeBase + row < N) *(uint4*)(featB + c * 16) = v;
    }
}

// ---------------------------------------------------------------------------
// Kernel 2: fused aggregate (r9-measured version, byte-identical logic).
// One wave per node; lane l owns features 2l,2l+1 (head hm=l>>4).
// Cooperative edge weights: 1 exp/lane per 16 edges; shfl redistribution.
// ---------------------------------------------------------------------------
__global__ __launch_bounds__(256) void aggregate_kernel(
    const __half* __restrict__ feat, const float* __restrict__ el,
    const float* __restrict__ er, const int* __restrict__ off,
    const int* __restrict__ src, const float* __restrict__ bias,
    float* __restrict__ out, int N)
{
    const int wid = (int)((blockIdx.x * blockDim.x + threadIdx.x) >> 6);
    const int l = threadIdx.x & 63;
    if (wid >= N) return;
    const int n = __builtin_amdgcn_readfirstlane(wid);   // SGPR node id
    const int s = off[n];                                // s_load
    const int e = off[n + 1];                            // s_load
    const int f0 = 2 * l;
    const int hm = l >> 4;
    const float b0 = bias[f0], b1 = bias[f0 + 1];
    float* outp = out + (size_t)n * 128;
    if (s >= e) {
        outp[f0] = fmaxf(b0, 0.f);
        outp[f0 + 1] = fmaxf(b1, 0.f);
        return;
    }

    const float er_mine = er[n * 4 + hm];
    const float er_coop = er[n * 4 + (l & 3)];
    float ax = 0.f, ay = 0.f, dn = 0.f;
    const unsigned int one2 = 0x3C003C00u;

    int ei = s;
    for (; ei + 16 <= e; ei += 16) {
        int sv[16];
#pragma unroll
        for (int k = 0; k < 16; ++k) sv[k] = src[ei + k];        // s_loads
        int svc = src[ei + (l >> 2)];                            // cooperative
        float sc = el[(size_t)svc * 4 + (l & 3)] + er_coop;
        sc = sc > 0.f ? sc : NEG_SLOPE * sc;
        float myw = __expf(sc);
        unsigned int g[16];
#pragma unroll
        for (int k = 0; k < 16; ++k)
            g[k] = *(const unsigned int*)(feat + (size_t)sv[k] * 128 + f0);
#pragma unroll
        for (int k = 0; k < 8; ++k) {
            float wa = __shfl(myw, 8 * k + hm);
            float wb = __shfl(myw, 8 * k + 4 + hm);
            unsigned int w2 = packw(wa, wb);
            unsigned int lo = __builtin_amdgcn_perm(g[2 * k + 1], g[2 * k], 0x05040100u);
            unsigned int hi = __builtin_amdgcn_perm(g[2 * k + 1], g[2 * k], 0x07060302u);
            ax = fdot2f(w2, lo, ax);
            ay = fdot2f(w2, hi, ay);
            dn = fdot2f(w2, one2, dn);
        }
    }
    if (ei + 8 <= e) {
        int sv[8];
#pragma unroll
        for (int k = 0; k < 8; ++k) sv[k] = src[ei + k];
        int svc = src[ei + ((l >> 2) & 7)];
        float sc = el[(size_t)svc * 4 + (l & 3)] + er_coop;
        sc = sc > 0.f ? sc : NEG_SLOPE * sc;
        float myw = __expf(sc);
        unsigned int g[8];
#pragma unroll
        for (int k = 0; k < 8; ++k)
            g[k] = *(const unsigned int*)(feat + (size_t)sv[k] * 128 + f0);
#pragma unroll
        for (int k = 0; k < 4; ++k) {
            float wa = __shfl(myw, 8 * k + hm);
            float wb = __shfl(myw, 8 * k + 4 + hm);
            unsigned int w2 = packw(wa, wb);
            unsigned int lo = __builtin_amdgcn_perm(g[2 * k + 1], g[2 * k], 0x05040100u);
            unsigned int hi = __builtin_amdgcn_perm(g[2 * k + 1], g[2 * k], 0x07060302u);
            ax = fdot2f(w2, lo, ax);
            ay = fdot2f(w2, hi, ay);
            dn = fdot2f(w2, one2, dn);
        }
        ei += 8;
    }
    if (ei + 4 <= e) {
        int sv0 = src[ei], sv1 = src[ei + 1], sv2 = src[ei + 2], sv3 = src[ei + 3];
        float e0 = el[(size_t)sv0 * 4 + hm], e1 = el[(size_t)sv1 * 4 + hm];
        float e2 = el[(size_t)sv2 * 4 + hm], e3 = el[(size_t)sv3 * 4 + hm];
        unsigned int g0 = *(const unsigned int*)(feat + (size_t)sv0 * 128 + f0);
        unsigned int g1 = *(const unsigned int*)(feat + (size_t)sv1 * 128 + f0);
        unsigned int g2 = *(const unsigned int*)(feat + (size_t)sv2 * 128 + f0);
        unsigned int g3 = *(const unsigned int*)(feat + (size_t)sv3 * 128 + f0);
        float s0 = e0 + er_mine, s1 = e1 + er_mine, s2 = e2 + er_mine, s3 = e3 + er_mine;
        s0 = s0 > 0.f ? s0 : NEG_SLOPE * s0;
        s1 = s1 > 0.f ? s1 : NEG_SLOPE * s1;
        s2 = s2 > 0.f ? s2 : NEG_SLOPE * s2;
        s3 = s3 > 0.f ? s3 : NEG_SLOPE * s3;
        unsigned int w2a = packw(__expf(s0), __expf(s1));
        unsigned int w2b = packw(__expf(s2), __expf(s3));
        unsigned int lo = __builtin_amdgcn_perm(g1, g0, 0x05040100u);
        unsigned int hi = __builtin_amdgcn_perm(g1, g0, 0x07060302u);
        ax = fdot2f(w2a, lo, ax); ay = fdot2f(w2a, hi, ay); dn = fdot2f(w2a, one2, dn);
        lo = __builtin_amdgcn_perm(g3, g2, 0x05040100u);
        hi = __builtin_amdgcn_perm(g3, g2, 0x07060302u);
        ax = fdot2f(w2b, lo, ax); ay = fdot2f(w2b, hi, ay); dn = fdot2f(w2b, one2, dn);
        ei += 4;
    }
    for (; ei < e; ++ei) {                               // <=3 tail edges
        int sv = src[ei];
        float sc = el[(size_t)sv * 4 + hm] + er_mine;
        sc = sc > 0.f ? sc : NEG_SLOPE * sc;
        float w = __expf(sc);
        __half2 gh = *(const __half2*)(feat + (size_t)sv * 128 + f0);
        float2 fv = __half22float2(gh);
        ax += w * fv.x; ay += w * fv.y; dn += w;
    }
    const float inv = 1.f / dn;
    *(float2*)(outp + f0) = make_float2(fmaxf(ax * inv + b0, 0.f),
                                        fmaxf(ay * inv + b1, 0.f));
}

// ---------------------------------------------------------------------------
extern "C" void kernel_launch(void* const* d_in, const int* in_sizes, int n_in,
                              void* d_out, int out_size, void* d_ws, size_t ws_size,
                              hipStream_t stream)
{
    const float* h      = (const float*)d_in[0];
    const int*   src    = (const int*)d_in[1];
    const int*   dst    = (const int*)d_in[2];
    const float* W      = (const float*)d_in[3];
    const float* attn_l = (const float*)d_in[4];
    const float* attn_r = (const float*)d_in[5];
    const float* bias   = (const float*)d_in[6];
    const int N = in_sizes[0] / 128;
    const int E = in_sizes[1];
    float* out = (float*)d_out;

    // workspace (all offsets multiples of 16B)
    char* ws = (char*)d_ws;
    __half* feat = (__half*)ws;            ws += (size_t)N * 128 * sizeof(__half); // 25.6MB
    float*  el   = (float*)ws;             ws += (size_t)N * 4 * sizeof(float);    // 1.6MB
    float*  er   = (float*)ws;             ws += (size_t)N * 4 * sizeof(float);    // 1.6MB
    __half* w16t = (__half*)ws;            ws += 128 * 128 * sizeof(__half);       // 32KB
    __half* al16 = (__half*)ws;            ws += 256;
    __half* ar16 = (__half*)ws;            ws += 256;
    int*    off  = (int*)ws;

    hipLaunchKernelGGL(prep_seg_kernel, dim3(64 + (E + 255) / 256), dim3(256), 0, stream,
                       W, w16t, attn_l, attn_r, al16, ar16, dst, off, E, N);
    hipLaunchKernelGGL(proj_kernel, dim3((N + 127) / 128), dim3(512), 0, stream,
                       h, w16t, al16, ar16, feat, el, er, N);
    hipLaunchKernelGGL(aggregate_kernel, dim3((N + 3) / 4), dim3(256), 0, stream,
                       feat, el, er, off, src, bias, out, N);
}